// Round 1
// baseline (88.381 us; speedup 1.0000x reference)
//
#include <hip/hip_runtime.h>

// out[b,n] = sum_m exp(-||qp[b,n,:2]-sp[b,m,:2]||) * f[b,m] / sum_m exp(-...)
// Shapes: qp [4,4096,3], sp [4,8192,3], feats [4,8192,1], out [4,4096,1] fp32.
//
// R10: dur_us = ~40us harness ws-poison fill (unavoidable, fillBufferAligned
// 256MiB @ 6.7TB/s) + ~40us mfe_main + ~7us small dispatches. mfe_main model:
// 94 cyc/(j,k) = 64 trans (4x16cyc blocking) + 10..20 VALU + ~10 LDS/stage.
// This round kills the LDS component: scene pairs are wave-uniform, so stage
// them once (pre-kernel) into interleaved float4s in ws and read them in main
// via block-uniform const-restrict loads -> compiler promotes to s_load on the
// SCALAR pipe (zero vector-issue cost, operands land in SGPR pairs that VOP3P
// can consume directly, 1 sgpr operand per instr). Also deletes the stage
// phase, __syncthreads, and the separate memset dispatch (folded into pre).
// Predict main ~31-34us, total ~79-82us.

#define B_DIM   4
#define N_DIM   4096
#define M_DIM   8192
#define NQ      (B_DIM * N_DIM)     // 16384
#define THREADS 256
#define QPT     4                   // queries per thread
#define QPB     (THREADS * QPT)     // 1024 queries per block
#define QGROUPS (NQ / QPB)          // 16
#define SPLITS  64                  // M splits (blockIdx.y) -> 1024 blocks
#define CHUNK   (M_DIM / SPLITS)    // 128 scene points per block
#define PAIRS   (CHUNK / 2)         // 64 point-pairs
#define NPAIR   (B_DIM * M_DIM / 2) // 16384 total point-pairs

typedef float v2f __attribute__((ext_vector_type(2)));

#define L2C 2.0813689810056077f     // (log2 e)^2

// Pack scene points into pair-interleaved float4s:
//   pxz[2p]   = {x0, x1, y0, y1}
//   pxz[2p+1] = {L2*(x0^2+y0^2), L2*(x1^2+y1^2), f0, f1}
// and zero the psw/pswf accumulators (replaces hipMemsetAsync).
__global__ __launch_bounds__(256) void mfe_pre(
    const float* __restrict__ sp,
    const float* __restrict__ feats,
    float* __restrict__ psw,
    float* __restrict__ pswf,
    float4* __restrict__ pxz)
{
    const int p = blockIdx.x * 256 + threadIdx.x;   // 0..NPAIR-1 == 0..NQ-1
    psw[p]  = 0.0f;                                  // NQ == NPAIR == 16384
    pswf[p] = 0.0f;
    const int b  = p >> 12;                          // / (M_DIM/2)
    const int pr = p & 4095;
    const int m0 = b * M_DIM + 2 * pr;
    const float x0 = sp[m0 * 3 + 0], y0 = sp[m0 * 3 + 1];
    const float x1 = sp[m0 * 3 + 3], y1 = sp[m0 * 3 + 4];
    pxz[2 * p]     = make_float4(x0, x1, y0, y1);
    pxz[2 * p + 1] = make_float4(L2C * fmaf(x0, x0, y0 * y0),
                                 L2C * fmaf(x1, x1, y1 * y1),
                                 feats[m0], feats[m0 + 1]);
}

__global__ __launch_bounds__(THREADS) void mfe_main(
    const float* __restrict__ qp,     // [B,N,3]
    const float4* __restrict__ pxz,   // [NPAIR][2] packed pairs
    float* __restrict__ psw,          // [NQ] zeroed accumulator
    float* __restrict__ pswf)         // [NQ] zeroed accumulator
{
    const int tid  = threadIdx.x;
    const int qg   = blockIdx.x;           // 0..QGROUPS-1
    const int s    = blockIdx.y;           // 0..SPLITS-1
    const int lane = tid & 63;
    const int w    = tid >> 6;
    const int qbase = qg * QPB + w * (QPT * 64) + lane;  // +k*64, k=0..3
    const int b     = qg / (N_DIM / QPB);  // batch (uniform per block)
    const int pbase = 2 * (b * (M_DIM / 2) + s * PAIRS); // uniform, float4 idx

    // Per-query constants, splatted into pairs ONCE (movs outside the loop).
    // t = L2*d2 = ca*x + cb*y + (z + q2)
    v2f caS[QPT], cbS[QPT], q2S[QPT];
    #pragma unroll
    for (int k = 0; k < QPT; ++k) {
        const int q = qbase + k * 64;
        const float qx = qp[q * 3 + 0];
        const float qy = qp[q * 3 + 1];
        const float ca = -2.0f * L2C * qx;
        const float cb = -2.0f * L2C * qy;
        const float q2 = L2C * fmaf(qx, qx, qy * qy);
        caS[k] = (v2f){ ca, ca };
        cbS[k] = (v2f){ cb, cb };
        q2S[k] = (v2f){ q2, q2 };
    }

    v2f sw[QPT], swf[QPT];
    #pragma unroll
    for (int k = 0; k < QPT; ++k) { sw[k] = (v2f){0.f, 0.f}; swf[k] = (v2f){0.f, 0.f}; }

    // Scene pairs: block-uniform, invariant, 32B-contiguous per j ->
    // s_load_dwordx8 on the scalar pipe; zero vector-issue cost.
    #pragma unroll 4
    for (int j = 0; j < PAIRS; ++j) {
        const float4 XY = pxz[pbase + 2 * j];
        const float4 ZF = pxz[pbase + 2 * j + 1];
        const v2f X = { XY.x, XY.y };
        const v2f Y = { XY.z, XY.w };
        const v2f Z = { ZF.x, ZF.y };
        const v2f F = { ZF.z, ZF.w };

        #pragma unroll
        for (int k = 0; k < QPT; ++k) {
            // t = ca*X + cb*Y + (Z + q2) — pure element-wise v2f,
            // each op has exactly one (scalar-pair) uniform operand.
            const v2f t = __builtin_elementwise_fma(
                caS[k], X, __builtin_elementwise_fma(cbS[k], Y, Z + q2S[k]));
            v2f wv;                        // abs/neg fold into src modifiers
            wv.x = __builtin_amdgcn_exp2f(-__builtin_amdgcn_sqrtf(__builtin_fabsf(t.x)));
            wv.y = __builtin_amdgcn_exp2f(-__builtin_amdgcn_sqrtf(__builtin_fabsf(t.y)));
            sw[k]  = sw[k] + wv;
            swf[k] = __builtin_elementwise_fma(wv, F, swf[k]);
        }
    }

    #pragma unroll
    for (int k = 0; k < QPT; ++k) {
        const int q = qbase + k * 64;
        atomicAdd(&psw[q],  sw[k].x  + sw[k].y);   // fire-and-forget
        atomicAdd(&pswf[q], swf[k].x + swf[k].y);
    }
}

__global__ __launch_bounds__(256) void mfe_div(
    const float* __restrict__ psw,
    const float* __restrict__ pswf,
    float* __restrict__ out)
{
    const int i = blockIdx.x * 256 + threadIdx.x;
    out[i] = pswf[i] / psw[i];
}

extern "C" void kernel_launch(void* const* d_in, const int* in_sizes, int n_in,
                              void* d_out, int out_size, void* d_ws, size_t ws_size,
                              hipStream_t stream) {
    const float* qp    = (const float*)d_in[0];
    const float* sp    = (const float*)d_in[1];
    const float* feats = (const float*)d_in[2];
    float* out = (float*)d_out;

    float* psw   = (float*)d_ws;                 // [NQ]
    float* pswf  = psw + NQ;                     // [NQ]
    float4* pxz  = (float4*)(pswf + NQ);         // [2*NPAIR], 16B-aligned (128KB off)

    mfe_pre<<<NPAIR / 256, 256, 0, stream>>>(sp, feats, psw, pswf, pxz);

    dim3 grid(QGROUPS, SPLITS);
    mfe_main<<<grid, THREADS, 0, stream>>>(qp, pxz, psw, pswf);
    mfe_div<<<NQ / 256, 256, 0, stream>>>(psw, pswf, out);
}

// Round 2
// 87.718 us; speedup vs baseline: 1.0076x; 1.0076x over previous
//
#include <hip/hip_runtime.h>

// out[b,n] = sum_m exp(-||qp[b,n,:2]-sp[b,m,:2]||) * f[b,m] / sum_m exp(-...)
// Shapes: qp [4,4096,3], sp [4,8192,3], feats [4,8192,1], out [4,4096,1] fp32.
//
// R11: R10 (uniform loads instead of LDS) was neutral -> loads' ISSUE cost was
// never the gap. Model: body = 4 trans (64cyc) + 5 pk-VALU (10cyc) = 74 floor,
// measured 94. Residual theory: unroll-group load-latency stalls (no SW
// pipelining across iterations; ~200-500cyc wait / 16 bodies ~ 10-20cyc/body).
// Fix: explicit ping-pong register prefetch of group g+1 (readfirstlane-forced
// scalar loads, branch-free via 128B-padded buffer) while computing group g.
// Predict main ~33-35us, total ~80-82us. If neutral: issue-port serialization
// floor (trans blocks vector issue, no cross-wave trans overlap) -> roofline.

#define B_DIM   4
#define N_DIM   4096
#define M_DIM   8192
#define NQ      (B_DIM * N_DIM)     // 16384
#define THREADS 256
#define QPT     4                   // queries per thread
#define QPB     (THREADS * QPT)     // 1024 queries per block
#define QGROUPS (NQ / QPB)          // 16
#define SPLITS  64                  // M splits (blockIdx.y) -> 1024 blocks
#define CHUNK   (M_DIM / SPLITS)    // 128 scene points per block
#define PAIRS   (CHUNK / 2)         // 64 point-pairs
#define NPAIR   (B_DIM * M_DIM / 2) // 16384 total point-pairs
#define GJ      4                   // pairs per prefetch group
#define NG      (PAIRS / GJ)        // 16 groups

typedef float v2f __attribute__((ext_vector_type(2)));

#define L2C 2.0813689810056077f     // (log2 e)^2

// Pack scene points into pair-interleaved float4s:
//   pxz[2p]   = {x0, x1, y0, y1}
//   pxz[2p+1] = {L2*(x0^2+y0^2), L2*(x1^2+y1^2), f0, f1}
// and zero the psw/pswf accumulators (replaces hipMemsetAsync).
__global__ __launch_bounds__(256) void mfe_pre(
    const float* __restrict__ sp,
    const float* __restrict__ feats,
    float* __restrict__ psw,
    float* __restrict__ pswf,
    float4* __restrict__ pxz)
{
    const int p = blockIdx.x * 256 + threadIdx.x;   // 0..NPAIR-1 == 0..NQ-1
    psw[p]  = 0.0f;                                  // NQ == NPAIR == 16384
    pswf[p] = 0.0f;
    const int b  = p >> 12;                          // / (M_DIM/2)
    const int pr = p & 4095;
    const int m0 = b * M_DIM + 2 * pr;
    const float x0 = sp[m0 * 3 + 0], y0 = sp[m0 * 3 + 1];
    const float x1 = sp[m0 * 3 + 3], y1 = sp[m0 * 3 + 4];
    pxz[2 * p]     = make_float4(x0, x1, y0, y1);
    pxz[2 * p + 1] = make_float4(L2C * fmaf(x0, x0, y0 * y0),
                                 L2C * fmaf(x1, x1, y1 * y1),
                                 feats[m0], feats[m0 + 1]);
}

__global__ __launch_bounds__(THREADS) void mfe_main(
    const float* __restrict__ qp,     // [B,N,3]
    const float4* __restrict__ pxz,   // [NPAIR][2] packed pairs (+8 pad)
    float* __restrict__ psw,          // [NQ] zeroed accumulator
    float* __restrict__ pswf)         // [NQ] zeroed accumulator
{
    const int tid  = threadIdx.x;
    const int qg   = blockIdx.x;           // 0..QGROUPS-1
    const int s    = blockIdx.y;           // 0..SPLITS-1
    const int lane = tid & 63;
    const int w    = tid >> 6;
    const int qbase = qg * QPB + w * (QPT * 64) + lane;  // +k*64, k=0..3
    const int b     = qg / (N_DIM / QPB);  // batch (uniform per block)
    // Force provable uniformity so the backend emits s_load (scalar pipe).
    const int pbase = __builtin_amdgcn_readfirstlane(
        2 * (b * (M_DIM / 2) + s * PAIRS));              // float4 index

    // Per-query constants, splatted into pairs ONCE (movs outside the loop).
    // t = L2*d2 = ca*x + cb*y + (z + q2)
    v2f caS[QPT], cbS[QPT], q2S[QPT];
    #pragma unroll
    for (int k = 0; k < QPT; ++k) {
        const int q = qbase + k * 64;
        const float qx = qp[q * 3 + 0];
        const float qy = qp[q * 3 + 1];
        const float ca = -2.0f * L2C * qx;
        const float cb = -2.0f * L2C * qy;
        const float q2 = L2C * fmaf(qx, qx, qy * qy);
        caS[k] = (v2f){ ca, ca };
        cbS[k] = (v2f){ cb, cb };
        q2S[k] = (v2f){ q2, q2 };
    }

    v2f sw[QPT], swf[QPT];
    #pragma unroll
    for (int k = 0; k < QPT; ++k) { sw[k] = (v2f){0.f, 0.f}; swf[k] = (v2f){0.f, 0.f}; }

    // Software-pipelined scene loads: ping-pong register groups, prefetch
    // group g+1 while computing group g. Branch-free: the last prefetch
    // overruns into the next chunk / 128B pad (loaded, never used).
    float4 XYb[2][GJ], ZFb[2][GJ];
    #pragma unroll
    for (int t0 = 0; t0 < GJ; ++t0) {
        XYb[0][t0] = pxz[pbase + 2 * t0];
        ZFb[0][t0] = pxz[pbase + 2 * t0 + 1];
    }

    #pragma unroll 2
    for (int g = 0; g < NG; ++g) {
        const int cur = g & 1, nxt = cur ^ 1;   // static under unroll 2
        const int pbn = pbase + 2 * GJ * (g + 1);
        #pragma unroll
        for (int t0 = 0; t0 < GJ; ++t0) {       // prefetch next group
            XYb[nxt][t0] = pxz[pbn + 2 * t0];
            ZFb[nxt][t0] = pxz[pbn + 2 * t0 + 1];
        }

        #pragma unroll
        for (int jj = 0; jj < GJ; ++jj) {
            const float4 XY = XYb[cur][jj];
            const float4 ZF = ZFb[cur][jj];
            const v2f X = { XY.x, XY.y };
            const v2f Y = { XY.z, XY.w };
            const v2f Z = { ZF.x, ZF.y };
            const v2f F = { ZF.z, ZF.w };

            #pragma unroll
            for (int k = 0; k < QPT; ++k) {
                // t = ca*X + cb*Y + (Z + q2) — pure element-wise v2f
                const v2f t = __builtin_elementwise_fma(
                    caS[k], X, __builtin_elementwise_fma(cbS[k], Y, Z + q2S[k]));
                v2f wv;                    // abs/neg fold into src modifiers
                wv.x = __builtin_amdgcn_exp2f(-__builtin_amdgcn_sqrtf(__builtin_fabsf(t.x)));
                wv.y = __builtin_amdgcn_exp2f(-__builtin_amdgcn_sqrtf(__builtin_fabsf(t.y)));
                sw[k]  = sw[k] + wv;
                swf[k] = __builtin_elementwise_fma(wv, F, swf[k]);
            }
        }
    }

    #pragma unroll
    for (int k = 0; k < QPT; ++k) {
        const int q = qbase + k * 64;
        atomicAdd(&psw[q],  sw[k].x  + sw[k].y);   // fire-and-forget
        atomicAdd(&pswf[q], swf[k].x + swf[k].y);
    }
}

__global__ __launch_bounds__(256) void mfe_div(
    const float* __restrict__ psw,
    const float* __restrict__ pswf,
    float* __restrict__ out)
{
    const int i = blockIdx.x * 256 + threadIdx.x;
    out[i] = pswf[i] / psw[i];
}

extern "C" void kernel_launch(void* const* d_in, const int* in_sizes, int n_in,
                              void* d_out, int out_size, void* d_ws, size_t ws_size,
                              hipStream_t stream) {
    const float* qp    = (const float*)d_in[0];
    const float* sp    = (const float*)d_in[1];
    const float* feats = (const float*)d_in[2];
    float* out = (float*)d_out;

    float* psw   = (float*)d_ws;                 // [NQ]
    float* pswf  = psw + NQ;                     // [NQ]
    float4* pxz  = (float4*)(pswf + NQ);         // [2*NPAIR]+8 pad, 16B-aligned

    mfe_pre<<<NPAIR / 256, 256, 0, stream>>>(sp, feats, psw, pswf, pxz);

    dim3 grid(QGROUPS, SPLITS);
    mfe_main<<<grid, THREADS, 0, stream>>>(qp, pxz, psw, pswf);
    mfe_div<<<NQ / 256, 256, 0, stream>>>(psw, pswf, out);
}

// Round 4
// 87.117 us; speedup vs baseline: 1.0145x; 1.0069x over previous
//
#include <hip/hip_runtime.h>

// out[b,n] = sum_m exp(-||qp[b,n,:2]-sp[b,m,:2]||) * f[b,m] / sum_m exp(-...)
// Shapes: qp [4,4096,3], sp [4,8192,3], feats [4,8192,1], out [4,4096,1] fp32.
//
// R13: R12's pk inline asm broke correctness (absmax 1.66 ~ hi-lane wrong ->
// op_sel_hi default strikes again, 3rd time). Revert to builtin math (R9,
// correct by construction), KEEP the .bss accumulator + self-cleaning div
// (isolates that change; deletes pre/memset dispatch).
// Port model (now exact): per-body issue cycles = 32 (2 v_sqrt) + 32 (2 v_exp)
// + ~20 (10 scalar VALU) + ~5 (LDS/loop) = ~94 = measured -> issue port 96%
// saturated; memory restructurings neutral because port-bound. Only levers:
// fewer port cycles (pk packing, -10cyc -> R14 with explicit op_sel) and
// dispatch cleanup (this round).
// Predict: pass @ absmax ~3e-5, total ~84-86us (87.7 - dispatch/gap savings).

#define B_DIM   4
#define N_DIM   4096
#define M_DIM   8192
#define NQ      (B_DIM * N_DIM)     // 16384
#define THREADS 256
#define QPT     4                   // queries per thread
#define QPB     (THREADS * QPT)     // 1024 queries per block
#define QGROUPS (NQ / QPB)          // 16
#define SPLITS  64                  // M splits (blockIdx.y) -> 1024 blocks
#define CHUNK   (M_DIM / SPLITS)    // 128 scene points per block
#define PAIRS   (CHUNK / 2)         // 64 point-pairs

typedef float v2f __attribute__((ext_vector_type(2)));

#define L2C 2.0813689810056077f     // (log2 e)^2

// Accumulators live in .bss (zero-initialized at module load), NOT in the
// harness-poisoned workspace. mfe_div re-zeros after reading, so the
// zero-invariant holds across graph replays. (Also self-healing: if main
// ever runs k times before div, both sums scale by k and the ratio is
// unchanged.) No memset dispatch needed.
__device__ float g_psw[NQ];
__device__ float g_pswf[NQ];

__global__ __launch_bounds__(THREADS) void mfe_main(
    const float* __restrict__ qp,     // [B,N,3]
    const float* __restrict__ sp,     // [B,M,3]
    const float* __restrict__ feats)  // [B,M,1]
{
    __shared__ float4 xy2[PAIRS];          // {x0, x1, y0, y1} : 1 KB
    __shared__ float4 zf2[PAIRS];          // {z0, z1, f0, f1} : 1 KB

    const int tid  = threadIdx.x;
    const int qg   = blockIdx.x;           // 0..QGROUPS-1
    const int s    = blockIdx.y;           // 0..SPLITS-1
    const int lane = tid & 63;
    const int w    = tid >> 6;
    const int qbase = qg * QPB + w * (QPT * 64) + lane;  // +k*64, k=0..3
    const int b     = qg / (N_DIM / QPB);  // batch (uniform per block)

    // Stage: threads 0..63 each build one point-pair (z precomputed here).
    if (tid < PAIRS) {
        const int m0 = b * M_DIM + s * CHUNK + 2 * tid;
        const float x0 = sp[m0 * 3 + 0], y0 = sp[m0 * 3 + 1];
        const float x1 = sp[m0 * 3 + 3], y1 = sp[m0 * 3 + 4];
        const float f0 = feats[m0], f1 = feats[m0 + 1];
        xy2[tid] = make_float4(x0, x1, y0, y1);
        zf2[tid] = make_float4(L2C * fmaf(x0, x0, y0 * y0),
                               L2C * fmaf(x1, x1, y1 * y1), f0, f1);
    }

    // Per-query constants, splatted into pairs ONCE (movs outside the loop).
    // t = L2*d2 = ca*x + cb*y + (z + q2)
    v2f caS[QPT], cbS[QPT], q2S[QPT];
    #pragma unroll
    for (int k = 0; k < QPT; ++k) {
        const int q = qbase + k * 64;
        const float qx = qp[q * 3 + 0];
        const float qy = qp[q * 3 + 1];
        const float ca = -2.0f * L2C * qx;
        const float cb = -2.0f * L2C * qy;
        const float q2 = L2C * fmaf(qx, qx, qy * qy);
        caS[k] = (v2f){ ca, ca };
        cbS[k] = (v2f){ cb, cb };
        q2S[k] = (v2f){ q2, q2 };
    }

    v2f sw[QPT], swf[QPT];
    #pragma unroll
    for (int k = 0; k < QPT; ++k) { sw[k] = (v2f){0.f, 0.f}; swf[k] = (v2f){0.f, 0.f}; }

    __syncthreads();

    #pragma unroll 8
    for (int j = 0; j < PAIRS; ++j) {
        const float4 XY = xy2[j];          // wave-uniform addr -> broadcast
        const float4 ZF = zf2[j];
        const v2f X = { XY.x, XY.y };      // adjacent regs straight from b128
        const v2f Y = { XY.z, XY.w };
        const v2f Z = { ZF.x, ZF.y };
        const v2f F = { ZF.z, ZF.w };

        #pragma unroll
        for (int k = 0; k < QPT; ++k) {
            // t = ca*X + cb*Y + (Z + q2) — pure element-wise v2f
            const v2f t = __builtin_elementwise_fma(
                caS[k], X, __builtin_elementwise_fma(cbS[k], Y, Z + q2S[k]));
            v2f wv;                        // abs/neg fold into src modifiers
            wv.x = __builtin_amdgcn_exp2f(-__builtin_amdgcn_sqrtf(__builtin_fabsf(t.x)));
            wv.y = __builtin_amdgcn_exp2f(-__builtin_amdgcn_sqrtf(__builtin_fabsf(t.y)));
            sw[k]  = sw[k] + wv;
            swf[k] = __builtin_elementwise_fma(wv, F, swf[k]);
        }
    }

    #pragma unroll
    for (int k = 0; k < QPT; ++k) {
        const int q = qbase + k * 64;
        atomicAdd(&g_psw[q],  sw[k].x  + sw[k].y);   // fire-and-forget
        atomicAdd(&g_pswf[q], swf[k].x + swf[k].y);
    }
}

__global__ __launch_bounds__(256) void mfe_div(float* __restrict__ out)
{
    const int i = blockIdx.x * 256 + threadIdx.x;
    out[i] = g_pswf[i] / g_psw[i];
    g_psw[i]  = 0.0f;                      // restore zero-invariant
    g_pswf[i] = 0.0f;
}

extern "C" void kernel_launch(void* const* d_in, const int* in_sizes, int n_in,
                              void* d_out, int out_size, void* d_ws, size_t ws_size,
                              hipStream_t stream) {
    const float* qp    = (const float*)d_in[0];
    const float* sp    = (const float*)d_in[1];
    const float* feats = (const float*)d_in[2];
    float* out = (float*)d_out;
    (void)d_ws; (void)ws_size;             // accumulators live in .bss

    dim3 grid(QGROUPS, SPLITS);
    mfe_main<<<grid, THREADS, 0, stream>>>(qp, sp, feats);
    mfe_div<<<NQ / 256, 256, 0, stream>>>(out);
}